// Round 1
// baseline (1231.211 us; speedup 1.0000x reference)
//
#include <hip/hip_runtime.h>
#include <math.h>

#define BB 8
#define CC 128
#define HH 64
#define WW 64
#define LL 4096
#define NP 24   // dt_rank(8) + 2*d_state(8)
#define SS 8

__device__ __forceinline__ float siluf(float x) { return x / (1.f + __expf(-x)); }
__device__ __forceinline__ float softplusf(float x) {
    return (x > 15.f) ? x : log1pf(__expf(x));
}

// scan-index t -> spatial position p for direction g (and its inverse for stores)
__device__ __forceinline__ int dmap(int g, int t) {
    switch (g) {
        case 0: return t;
        case 1: return ((t & 63) << 6) | (t >> 6);
        case 2: return (LL - 1) - t;
        default: { int u = (LL - 1) - t; return ((u & 63) << 6) | (u >> 6); }
    }
}
// spatial position p -> scan index l for direction g
__device__ __forceinline__ int smap(int g, int p) {
    switch (g) {
        case 0: return p;
        case 1: return ((p & 63) << 6) | (p >> 6);
        case 2: return (LL - 1) - p;
        default: return (LL - 1) - (((p & 63) << 6) | (p >> 6));
    }
}

// ---------------- in_proj: (B,C,L) x  @ W(256,128)^T -> xi (B,C,L), z (B,L,C)
__global__ void k_inproj(const float* __restrict__ src, const float* __restrict__ w,
                         float* __restrict__ xi, float* __restrict__ z) {
    __shared__ float xt[CC][8];
    int blk = blockIdx.x;
    int b = blk / (LL / 8);
    int p0 = (blk % (LL / 8)) * 8;
    int tid = threadIdx.x;
    for (int i = tid; i < CC * 8; i += 256) {
        int c = i >> 3, pp = i & 7;
        xt[c][pp] = src[((size_t)b * CC + c) * LL + p0 + pp];
    }
    __syncthreads();
    int o = tid;  // 0..255 output channel
    float a0 = 0, a1 = 0, a2 = 0, a3 = 0, a4 = 0, a5 = 0, a6 = 0, a7 = 0;
    const float* wr = w + (size_t)o * CC;
    #pragma unroll 4
    for (int c = 0; c < CC; ++c) {
        float wv = wr[c];
        float4 v0 = *(const float4*)&xt[c][0];
        float4 v1 = *(const float4*)&xt[c][4];
        a0 = fmaf(wv, v0.x, a0); a1 = fmaf(wv, v0.y, a1);
        a2 = fmaf(wv, v0.z, a2); a3 = fmaf(wv, v0.w, a3);
        a4 = fmaf(wv, v1.x, a4); a5 = fmaf(wv, v1.y, a5);
        a6 = fmaf(wv, v1.z, a6); a7 = fmaf(wv, v1.w, a7);
    }
    float acc[8] = {a0, a1, a2, a3, a4, a5, a6, a7};
    if (o < CC) {
        float* dst = xi + ((size_t)b * CC + o) * LL + p0;
        #pragma unroll
        for (int pp = 0; pp < 8; ++pp) dst[pp] = acc[pp];
    } else {
        int oz = o - CC;
        #pragma unroll
        for (int pp = 0; pp < 8; ++pp)
            z[((size_t)b * LL + p0 + pp) * CC + oz] = acc[pp];
    }
}

// ---------------- depthwise 3x3 conv, pad 1, (B,C,64,64); optional silu
__global__ void k_dwconv(const float* __restrict__ src, const float* __restrict__ w,
                         const float* __restrict__ bias, float* __restrict__ dst,
                         int do_silu) {
    int idx = blockIdx.x * 256 + threadIdx.x;  // < B*C*L
    int p = idx & (LL - 1);
    int c = (idx >> 12) & (CC - 1);
    int b = idx >> 19;
    int h = p >> 6, w0 = p & 63;
    const float* sp = src + ((size_t)b * CC + c) * LL;
    const float* wc = w + c * 9;
    float acc = bias[c];
    #pragma unroll
    for (int kh = 0; kh < 3; ++kh) {
        int hh = h + kh - 1;
        if ((unsigned)hh < 64u) {
            #pragma unroll
            for (int kw = 0; kw < 3; ++kw) {
                int ww = w0 + kw - 1;
                if ((unsigned)ww < 64u) acc = fmaf(sp[hh * 64 + ww], wc[kh * 3 + kw], acc);
            }
        }
    }
    if (do_silu) acc = siluf(acc);
    dst[idx] = acc;
}

// ---------------- causal depthwise conv1d k=4 + bias + silu, (B,C,L)
__global__ void k_conv1d(const float* __restrict__ src, const float* __restrict__ w,
                         const float* __restrict__ bias, float* __restrict__ dst) {
    int idx = blockIdx.x * 256 + threadIdx.x;
    int l = idx & (LL - 1);
    int c = (idx >> 12) & (CC - 1);
    int b = idx >> 19;
    const float* sp = src + ((size_t)b * CC + c) * LL;
    const float* wc = w + c * 4;
    float acc = bias[c];
    #pragma unroll
    for (int k = 0; k < 4; ++k) {
        int ll = l - 3 + k;
        if (ll >= 0) acc = fmaf(sp[ll], wc[k], acc);
    }
    dst[idx] = siluf(acc);
}

// ---------------- x_proj: (B,C,L) -> proj (B,G,L,24) in scan order
template <int G>
__global__ void k_proj(const float* __restrict__ src, const float* __restrict__ w,
                       float* __restrict__ dst) {
    __shared__ float xt[CC][64];
    __shared__ float prj[G][64][NP];
    int blk = blockIdx.x;
    int b = blk / (LL / 64);
    int p0 = (blk % (LL / 64)) * 64;
    int tid = threadIdx.x;
    for (int i = tid; i < CC * 64; i += 256) {
        int c = i >> 6, pp = i & 63;
        xt[c][pp] = src[((size_t)b * CC + c) * LL + p0 + pp];
    }
    __syncthreads();
    const int PAIRS = G * NP;          // 96 or 24
    const int PER = PAIRS / 4;         // 24 or 6
    int pp = tid & 63;
    int bp = tid >> 6;                 // 0..3
    float acc[PER];
    #pragma unroll
    for (int j = 0; j < PER; ++j) acc[j] = 0.f;
    for (int c = 0; c < CC; ++c) {
        float xv = xt[c][pp];
        #pragma unroll
        for (int j = 0; j < PER; ++j)
            acc[j] = fmaf(w[(bp + j * 4) * CC + c], xv, acc[j]);
    }
    #pragma unroll
    for (int j = 0; j < PER; ++j) {
        int pair = bp + j * 4;
        prj[pair / NP][pp][pair % NP] = acc[j];
    }
    __syncthreads();
    for (int i = tid; i < G * 64 * NP; i += 256) {
        int d = i % NP;
        int rest = i / NP;
        int ppp = rest & 63;
        int g = rest >> 6;
        int p = p0 + ppp;
        int l = (G == 4) ? smap(g, p) : p;
        dst[((size_t)(b * G + g) * LL + l) * NP + d] = prj[g][ppp][d];
    }
}

// ---------------- selective scan (wave-chunked 2-pass); G=4 atomic-acc, G=1 store
template <int G>
__global__ void k_scan(const float* __restrict__ proj, const float* __restrict__ xsrc,
                       const float* __restrict__ dtw, const float* __restrict__ dtb,
                       const float* __restrict__ Alog, const float* __restrict__ Dp,
                       float* __restrict__ ydst) {
    int wid = threadIdx.x >> 6;
    int lane = threadIdx.x & 63;
    int chain = blockIdx.x * 4 + wid;
    int c = chain & (CC - 1);
    int g = (G == 4) ? ((chain >> 7) & 3) : 0;
    int b = chain / (G * CC);
    int gc = g * CC + c;
    const float* pr = proj + (size_t)(b * G + g) * LL * NP;
    const float* xp = xsrc + ((size_t)b * CC + c) * LL;
    float dwv[SS], Av[SS];
    #pragma unroll
    for (int s = 0; s < SS; ++s) {
        dwv[s] = dtw[gc * SS + s];
        Av[s] = -expf(Alog[gc * SS + s]);
    }
    float bias = dtb[gc];
    float Dv = Dp[gc];
    float h[SS];
    #pragma unroll
    for (int s = 0; s < SS; ++s) h[s] = 0.f;
    float sumdt = 0.f;
    const int t0 = lane * 64;
    // pass 1: local chunk with h0 = 0
    for (int k = 0; k < 64; ++k) {
        int t = t0 + k;
        const float4* p4 = (const float4*)(pr + (size_t)t * NP);
        float4 r0 = p4[0], r1 = p4[1], b0 = p4[2], b1 = p4[3];
        float dt = softplusf(r0.x * dwv[0] + r0.y * dwv[1] + r0.z * dwv[2] + r0.w * dwv[3] +
                             r1.x * dwv[4] + r1.y * dwv[5] + r1.z * dwv[6] + r1.w * dwv[7] + bias);
        sumdt += dt;
        float xv = xp[dmap(g, t)];
        float dx = dt * xv;
        float Bb[SS] = {b0.x, b0.y, b0.z, b0.w, b1.x, b1.y, b1.z, b1.w};
        #pragma unroll
        for (int s = 0; s < SS; ++s) h[s] = fmaf(h[s], __expf(dt * Av[s]), dx * Bb[s]);
    }
    // chunk transition: A_chunk = exp(A*sum_dt), B_chunk = h
    float Ac[SS], Bc[SS];
    #pragma unroll
    for (int s = 0; s < SS; ++s) { Ac[s] = __expf(Av[s] * sumdt); Bc[s] = h[s]; }
    // inclusive Hillis-Steele scan of affine composition across 64 lanes
    #pragma unroll
    for (int off = 1; off < 64; off <<= 1) {
        #pragma unroll
        for (int s = 0; s < SS; ++s) {
            float Ap = __shfl_up(Ac[s], (unsigned)off);
            float Bp = __shfl_up(Bc[s], (unsigned)off);
            if (lane >= off) { Bc[s] = fmaf(Bp, Ac[s], Bc[s]); Ac[s] *= Ap; }
        }
    }
    // exclusive: h at chunk start
    #pragma unroll
    for (int s = 0; s < SS; ++s) {
        float hb = __shfl_up(Bc[s], 1u);
        h[s] = (lane > 0) ? hb : 0.f;
    }
    // pass 2: replay with true h_start, emit y
    for (int k = 0; k < 64; ++k) {
        int t = t0 + k;
        const float4* p4 = (const float4*)(pr + (size_t)t * NP);
        float4 r0 = p4[0], r1 = p4[1], b0 = p4[2], b1 = p4[3], c0 = p4[4], c1 = p4[5];
        float dt = softplusf(r0.x * dwv[0] + r0.y * dwv[1] + r0.z * dwv[2] + r0.w * dwv[3] +
                             r1.x * dwv[4] + r1.y * dwv[5] + r1.z * dwv[6] + r1.w * dwv[7] + bias);
        int p = dmap(g, t);
        float xv = xp[p];
        float dx = dt * xv;
        float Bb[SS] = {b0.x, b0.y, b0.z, b0.w, b1.x, b1.y, b1.z, b1.w};
        float Cb[SS] = {c0.x, c0.y, c0.z, c0.w, c1.x, c1.y, c1.z, c1.w};
        float y = Dv * xv;
        #pragma unroll
        for (int s = 0; s < SS; ++s) {
            h[s] = fmaf(h[s], __expf(dt * Av[s]), dx * Bb[s]);
            y = fmaf(h[s], Cb[s], y);
        }
        if (G == 4) atomicAdd(&ydst[((size_t)b * CC + c) * LL + p], y);
        else        ydst[((size_t)b * CC + c) * LL + t] = y;
    }
}

// ---------------- epilogue: [LN] -> *silu(z) -> @out_w^T ; y (B,C,L) -> dst (B,C,L)
template <bool DO_LN>
__global__ void k_epilogue(const float* __restrict__ ysrc, const float* __restrict__ zsrc,
                           const float* __restrict__ lng, const float* __restrict__ lnb,
                           const float* __restrict__ outw, float* __restrict__ dst) {
    __shared__ float yt[CC][66];
    __shared__ float mu_s[64], rs_s[64];
    int blk = blockIdx.x;
    int b = blk / (LL / 64);
    int p0 = (blk % (LL / 64)) * 64;
    int tid = threadIdx.x;
    for (int i = tid; i < CC * 64; i += 256) {
        int c = i >> 6, pp = i & 63;
        yt[c][pp] = ysrc[((size_t)b * CC + c) * LL + p0 + pp];
    }
    __syncthreads();
    if (DO_LN) {
        int pp = tid >> 2, q = tid & 3;
        float s = 0.f, ss = 0.f;
        for (int j = 0; j < 32; ++j) {
            float v = yt[q * 32 + j][pp];
            s += v; ss = fmaf(v, v, ss);
        }
        s += __shfl_xor(s, 1); ss += __shfl_xor(ss, 1);
        s += __shfl_xor(s, 2); ss += __shfl_xor(ss, 2);
        if (q == 0) {
            float mu = s * (1.f / 128.f);
            float var = ss * (1.f / 128.f) - mu * mu;
            mu_s[pp] = mu;
            rs_s[pp] = rsqrtf(var + 1e-5f);
        }
        __syncthreads();
    }
    // gate (+LN) in place
    for (int i = tid; i < CC * 64; i += 256) {
        int c = i & 127, pp = i >> 7;
        float v = yt[c][pp];
        if (DO_LN) v = fmaf((v - mu_s[pp]) * rs_s[pp], lng[c], lnb[c]);
        float zv = zsrc[((size_t)b * LL + p0 + pp) * CC + c];
        yt[c][pp] = v * siluf(zv);
    }
    __syncthreads();
    // out matmul: 128x128
    int o = tid & 127, ph = tid >> 7;
    float acc[32];
    #pragma unroll
    for (int j = 0; j < 32; ++j) acc[j] = 0.f;
    const float* wr = outw + (size_t)o * CC;
    for (int c = 0; c < CC; ++c) {
        float wv = wr[c];
        const float* row = &yt[c][ph * 32];
        #pragma unroll
        for (int j = 0; j < 32; ++j) acc[j] = fmaf(wv, row[j], acc[j]);
    }
    float* dp = dst + ((size_t)b * CC + o) * LL + p0 + ph * 32;
    #pragma unroll
    for (int j = 0; j < 32; ++j) dp[j] = acc[j];
}

// ---------------- final fusion: E0 = sigmoid(x . iw); out = (1-E0)*fi + E0*fr + x
__global__ void k_final(const float* __restrict__ x, const float* __restrict__ fi,
                        const float* __restrict__ fr, const float* __restrict__ iw,
                        float* __restrict__ out) {
    __shared__ float xt[CC][66];
    __shared__ float iws[CC];
    __shared__ float e_s[64];
    int blk = blockIdx.x;
    int b = blk / (LL / 64);
    int p0 = (blk % (LL / 64)) * 64;
    int tid = threadIdx.x;
    if (tid < CC) iws[tid] = iw[tid];
    for (int i = tid; i < CC * 64; i += 256) {
        int c = i >> 6, pp = i & 63;
        xt[c][pp] = x[((size_t)b * CC + c) * LL + p0 + pp];
    }
    __syncthreads();
    {
        int pp = tid >> 2, q = tid & 3;
        float s = 0.f;
        for (int j = 0; j < 32; ++j) {
            int c = q * 32 + j;
            s = fmaf(xt[c][pp], iws[c], s);
        }
        s += __shfl_xor(s, 1);
        s += __shfl_xor(s, 2);
        if (q == 0) e_s[pp] = 1.f / (1.f + __expf(-s));
    }
    __syncthreads();
    for (int i = tid; i < CC * 64; i += 256) {
        int c = i >> 6, pp = i & 63;
        size_t idx = ((size_t)b * CC + c) * LL + p0 + pp;
        float e = e_s[pp];
        out[idx] = (1.f - e) * fi[idx] + e * fr[idx] + xt[c][pp];
    }
}

extern "C" void kernel_launch(void* const* d_in, const int* in_sizes, int n_in,
                              void* d_out, int out_size, void* d_ws, size_t ws_size,
                              hipStream_t stream) {
    (void)in_sizes; (void)n_in; (void)out_size; (void)ws_size;
    const float* x       = (const float*)d_in[0];
    const float* s_inw   = (const float*)d_in[1];
    const float* s_convw = (const float*)d_in[2];
    const float* s_convb = (const float*)d_in[3];
    const float* s_xpw   = (const float*)d_in[4];
    const float* s_dtw   = (const float*)d_in[5];
    const float* s_dtb   = (const float*)d_in[6];
    const float* s_alog  = (const float*)d_in[7];
    const float* s_D     = (const float*)d_in[8];
    const float* s_lng   = (const float*)d_in[9];
    const float* s_lnb   = (const float*)d_in[10];
    const float* s_outw  = (const float*)d_in[11];
    const float* dw_w    = (const float*)d_in[12];
    const float* dw_b    = (const float*)d_in[13];
    const float* m_inw   = (const float*)d_in[14];
    const float* m_convw = (const float*)d_in[15];
    const float* m_convb = (const float*)d_in[16];
    const float* m_xpw   = (const float*)d_in[17];
    const float* m_dtw   = (const float*)d_in[18];
    const float* m_dtb   = (const float*)d_in[19];
    const float* m_alog  = (const float*)d_in[20];
    const float* m_D     = (const float*)d_in[21];
    const float* m_outw  = (const float*)d_in[22];
    const float* il_w    = (const float*)d_in[23];
    float* out = (float*)d_out;

    const size_t SZ1 = (size_t)BB * CC * LL;  // 4,194,304 floats
    float* ws  = (float*)d_ws;
    float* f_xi = ws;              // ss2d xi  -> mamba x_dw -> mamba ys
    float* f_z  = ws + SZ1;        // ss2d z   -> mamba z        (B,L,C)
    float* f_xc = ws + 2 * SZ1;    // ss2d xc  -> mamba xi -> f_refl
    float* f_y  = ws + 3 * SZ1;    // ss2d y-accum -> mamba xc
    float* f_pr = ws + 4 * SZ1;    // proj (B,4,L,24) / (B,L,24)

    dim3 blk(256);
    // ---- SS2D (global illumination) branch; f_illum lands in d_out
    k_inproj<<<BB * LL / 8, blk, 0, stream>>>(x, s_inw, f_xi, f_z);
    k_dwconv<<<(BB * CC * LL) / 256, blk, 0, stream>>>(f_xi, s_convw, s_convb, f_xc, 1);
    k_proj<4><<<BB * LL / 64, blk, 0, stream>>>(f_xc, s_xpw, f_pr);
    hipMemsetAsync(f_y, 0, SZ1 * sizeof(float), stream);
    k_scan<4><<<BB * 4 * CC / 4, blk, 0, stream>>>(f_pr, f_xc, s_dtw, s_dtb, s_alog, s_D, f_y);
    k_epilogue<true><<<BB * LL / 64, blk, 0, stream>>>(f_y, f_z, s_lng, s_lnb, s_outw, out);
    // ---- Mamba (local reflectance) branch
    k_dwconv<<<(BB * CC * LL) / 256, blk, 0, stream>>>(x, dw_w, dw_b, f_xi, 0);
    k_inproj<<<BB * LL / 8, blk, 0, stream>>>(f_xi, m_inw, f_xc, f_z);
    k_conv1d<<<(BB * CC * LL) / 256, blk, 0, stream>>>(f_xc, m_convw, m_convb, f_y);
    k_proj<1><<<BB * LL / 64, blk, 0, stream>>>(f_y, m_xpw, f_pr);
    k_scan<1><<<BB * CC / 4, blk, 0, stream>>>(f_pr, f_y, m_dtw, m_dtb, m_alog, m_D, f_xi);
    k_epilogue<false><<<BB * LL / 64, blk, 0, stream>>>(f_xi, f_z, s_lng, s_lnb, m_outw, f_xc);
    // ---- physics-prior gated fusion (+x); fi aliases out (read-before-write per element)
    k_final<<<BB * LL / 64, blk, 0, stream>>>(x, out, f_xc, il_w, out);
}

// Round 2
// 614.695 us; speedup vs baseline: 2.0030x; 2.0030x over previous
//
#include <hip/hip_runtime.h>
#include <math.h>

#define BB 8
#define CC 128
#define LL 4096
#define NP 24   // dt_rank(8) + 2*d_state(8)
#define SS 8

__device__ __forceinline__ float siluf(float x) { return x / (1.f + __expf(-x)); }
__device__ __forceinline__ float softplusf(float x) {
    return (x > 15.f) ? x : __logf(1.f + __expf(x));
}

// scan-index t -> spatial position p for direction g
__device__ __forceinline__ int dmap(int g, int t) {
    switch (g) {
        case 0: return t;
        case 1: return ((t & 63) << 6) | (t >> 6);
        case 2: return (LL - 1) - t;
        default: { int u = (LL - 1) - t; return ((u & 63) << 6) | (u >> 6); }
    }
}
// spatial position p -> scan index l for direction g
__device__ __forceinline__ int smap(int g, int p) {
    switch (g) {
        case 0: return p;
        case 1: return ((p & 63) << 6) | (p >> 6);
        case 2: return (LL - 1) - p;
        default: return (LL - 1) - (((p & 63) << 6) | (p >> 6)); }
}

// ---------------- in_proj: (B,C,L) x  @ W(256,128)^T -> xi (B,C,L), z (B,L,C)
__global__ void k_inproj(const float* __restrict__ src, const float* __restrict__ w,
                         float* __restrict__ xi, float* __restrict__ z) {
    __shared__ float xt[CC][8];
    int blk = blockIdx.x;
    int b = blk / (LL / 8);
    int p0 = (blk % (LL / 8)) * 8;
    int tid = threadIdx.x;
    for (int i = tid; i < CC * 8; i += 256) {
        int c = i >> 3, pp = i & 7;
        xt[c][pp] = src[((size_t)b * CC + c) * LL + p0 + pp];
    }
    __syncthreads();
    int o = tid;
    float a0 = 0, a1 = 0, a2 = 0, a3 = 0, a4 = 0, a5 = 0, a6 = 0, a7 = 0;
    const float* wr = w + (size_t)o * CC;
    #pragma unroll 4
    for (int c = 0; c < CC; ++c) {
        float wv = wr[c];
        float4 v0 = *(const float4*)&xt[c][0];
        float4 v1 = *(const float4*)&xt[c][4];
        a0 = fmaf(wv, v0.x, a0); a1 = fmaf(wv, v0.y, a1);
        a2 = fmaf(wv, v0.z, a2); a3 = fmaf(wv, v0.w, a3);
        a4 = fmaf(wv, v1.x, a4); a5 = fmaf(wv, v1.y, a5);
        a6 = fmaf(wv, v1.z, a6); a7 = fmaf(wv, v1.w, a7);
    }
    float acc[8] = {a0, a1, a2, a3, a4, a5, a6, a7};
    if (o < CC) {
        float* dst = xi + ((size_t)b * CC + o) * LL + p0;
        #pragma unroll
        for (int pp = 0; pp < 8; ++pp) dst[pp] = acc[pp];
    } else {
        int oz = o - CC;
        #pragma unroll
        for (int pp = 0; pp < 8; ++pp)
            z[((size_t)b * LL + p0 + pp) * CC + oz] = acc[pp];
    }
}

// ---------------- depthwise 3x3 conv, pad 1, (B,C,64,64); optional silu
__global__ void k_dwconv(const float* __restrict__ src, const float* __restrict__ w,
                         const float* __restrict__ bias, float* __restrict__ dst,
                         int do_silu) {
    int idx = blockIdx.x * 256 + threadIdx.x;
    int p = idx & (LL - 1);
    int c = (idx >> 12) & (CC - 1);
    int b = idx >> 19;
    int h = p >> 6, w0 = p & 63;
    const float* sp = src + ((size_t)b * CC + c) * LL;
    const float* wc = w + c * 9;
    float acc = bias[c];
    #pragma unroll
    for (int kh = 0; kh < 3; ++kh) {
        int hh = h + kh - 1;
        if ((unsigned)hh < 64u) {
            #pragma unroll
            for (int kw = 0; kw < 3; ++kw) {
                int ww = w0 + kw - 1;
                if ((unsigned)ww < 64u) acc = fmaf(sp[hh * 64 + ww], wc[kh * 3 + kw], acc);
            }
        }
    }
    if (do_silu) acc = siluf(acc);
    dst[idx] = acc;
}

// ---------------- causal depthwise conv1d k=4 + bias + silu, (B,C,L)
__global__ void k_conv1d(const float* __restrict__ src, const float* __restrict__ w,
                         const float* __restrict__ bias, float* __restrict__ dst) {
    int idx = blockIdx.x * 256 + threadIdx.x;
    int l = idx & (LL - 1);
    int c = (idx >> 12) & (CC - 1);
    int b = idx >> 19;
    const float* sp = src + ((size_t)b * CC + c) * LL;
    const float* wc = w + c * 4;
    float acc = bias[c];
    #pragma unroll
    for (int k = 0; k < 4; ++k) {
        int ll = l - 3 + k;
        if (ll >= 0) acc = fmaf(sp[ll], wc[k], acc);
    }
    dst[idx] = siluf(acc);
}

// ---------------- tiled transpose (B,C,L) -> (B,L,C)
__global__ void k_transpose(const float* __restrict__ src, float* __restrict__ dst) {
    __shared__ float t[64][65];
    int blk = blockIdx.x;
    int ct = blk & 1;            // C/64 = 2
    int pt = (blk >> 1) & 63;    // L/64 = 64
    int b  = blk >> 7;
    int c0 = ct * 64, p0 = pt * 64;
    int tid = threadIdx.x;
    int px = tid & 63, r0 = tid >> 6;
    for (int r = r0; r < 64; r += 4)
        t[r][px] = src[((size_t)b * CC + c0 + r) * LL + p0 + px];
    __syncthreads();
    for (int r = r0; r < 64; r += 4)
        dst[((size_t)b * LL + p0 + r) * CC + c0 + px] = t[px][r];
}

// ---------------- x_proj: xT (B,L,C) -> proj (B,G,L,24) in scan order
template <int G>
__global__ void k_proj(const float* __restrict__ src, const float* __restrict__ w,
                       float* __restrict__ dst) {
    __shared__ float xt[CC][66];
    __shared__ float prj[G][64][NP];
    int blk = blockIdx.x;
    int b = blk / (LL / 64);
    int p0 = (blk % (LL / 64)) * 64;
    int tid = threadIdx.x;
    for (int i = tid; i < CC * 64; i += 256) {
        int c = i & 127, pp = i >> 7;
        xt[c][pp] = src[((size_t)b * LL + p0 + pp) * CC + c];
    }
    __syncthreads();
    const int PAIRS = G * NP;
    const int PER = PAIRS / 4;
    int pp = tid & 63;
    int bp = tid >> 6;
    float acc[PER];
    #pragma unroll
    for (int j = 0; j < PER; ++j) acc[j] = 0.f;
    for (int c = 0; c < CC; ++c) {
        float xv = xt[c][pp];
        #pragma unroll
        for (int j = 0; j < PER; ++j)
            acc[j] = fmaf(w[(bp + j * 4) * CC + c], xv, acc[j]);
    }
    #pragma unroll
    for (int j = 0; j < PER; ++j) {
        int pair = bp + j * 4;
        prj[pair / NP][pp][pair % NP] = acc[j];
    }
    __syncthreads();
    for (int i = tid; i < G * 64 * NP; i += 256) {
        int d = i % NP;
        int rest = i / NP;
        int ppp = rest & 63;
        int g = rest >> 6;
        int p = p0 + ppp;
        int l = (G == 4) ? smap(g, p) : p;
        dst[((size_t)(b * G + g) * LL + l) * NP + d] = prj[g][ppp][d];
    }
}

// ---------------- S1: per-chunk local scan (h0=0) -> summaries (sumdt, h[8])
// grid: B*G*64 chunks, block 128 (lane = channel)
template <int G>
__global__ __launch_bounds__(128) void k_scan_chunk1(
        const float* __restrict__ proj, const float* __restrict__ xT,
        const float* __restrict__ dtw, const float* __restrict__ dtb,
        const float* __restrict__ Alog, float* __restrict__ summ) {
    __shared__ float rs[64 * NP];
    int blk = blockIdx.x;
    int chunk = blk & 63;
    int g = (G == 4) ? ((blk >> 6) & 3) : 0;
    int b = blk / (G * 64);
    int c = threadIdx.x;
    const float* pr = proj + ((size_t)(b * G + g) * LL + chunk * 64) * NP;
    for (int i = threadIdx.x; i < 64 * NP / 4; i += 128)
        ((float4*)rs)[i] = ((const float4*)pr)[i];
    int gc = g * CC + c;
    float dwv[SS], Av[SS];
    #pragma unroll
    for (int s = 0; s < SS; ++s) {
        dwv[s] = dtw[gc * SS + s];
        Av[s] = -expf(Alog[gc * SS + s]);
    }
    float bias = dtb[gc];
    __syncthreads();
    float h[SS];
    #pragma unroll
    for (int s = 0; s < SS; ++s) h[s] = 0.f;
    float sumdt = 0.f;
    const float* xb = xT + (size_t)b * LL * CC + c;
    for (int k = 0; k < 64; ++k) {
        int t = chunk * 64 + k;
        int p = (G == 4) ? dmap(g, t) : t;
        float xv = xb[(size_t)p * CC];
        const float4* r4 = (const float4*)(rs + k * NP);
        float4 ra = r4[0], rb = r4[1], b0 = r4[2], b1 = r4[3];
        float dt = softplusf(ra.x * dwv[0] + ra.y * dwv[1] + ra.z * dwv[2] + ra.w * dwv[3] +
                             rb.x * dwv[4] + rb.y * dwv[5] + rb.z * dwv[6] + rb.w * dwv[7] + bias);
        sumdt += dt;
        float dx = dt * xv;
        float Bb[SS] = {b0.x, b0.y, b0.z, b0.w, b1.x, b1.y, b1.z, b1.w};
        #pragma unroll
        for (int s = 0; s < SS; ++s) h[s] = fmaf(h[s], __expf(dt * Av[s]), dx * Bb[s]);
    }
    float* sp = summ + ((size_t)((b * G + g) * CC + c) * 64 + chunk) * 9;
    sp[0] = sumdt;
    #pragma unroll
    for (int s = 0; s < SS; ++s) sp[1 + s] = h[s];
}

// ---------------- S2: cross-chunk shuffle scan -> h_start per chunk
// block 256 = 4 waves, wave = one chain (b,g,c), lane = chunk
template <int G>
__global__ __launch_bounds__(256) void k_scan_chain(
        const float* __restrict__ summ, const float* __restrict__ Alog,
        float* __restrict__ hstart) {
    int wid = threadIdx.x >> 6, lane = threadIdx.x & 63;
    int chain = blockIdx.x * 4 + wid;       // = (b*G+g)*CC + c
    int c = chain & 127;
    int g = (G == 4) ? ((chain >> 7) & 3) : 0;
    int gc = g * CC + c;
    float Av[SS];
    #pragma unroll
    for (int s = 0; s < SS; ++s) Av[s] = -expf(Alog[gc * SS + s]);
    const float* sp = summ + ((size_t)chain * 64 + lane) * 9;
    float sumdt = sp[0];
    float Ac[SS], Bc[SS];
    #pragma unroll
    for (int s = 0; s < SS; ++s) { Ac[s] = __expf(Av[s] * sumdt); Bc[s] = sp[1 + s]; }
    #pragma unroll
    for (int off = 1; off < 64; off <<= 1) {
        #pragma unroll
        for (int s = 0; s < SS; ++s) {
            float Ap = __shfl_up(Ac[s], (unsigned)off);
            float Bp = __shfl_up(Bc[s], (unsigned)off);
            if (lane >= off) { Bc[s] = fmaf(Bp, Ac[s], Bc[s]); Ac[s] *= Ap; }
        }
    }
    float* hp = hstart + ((size_t)chain * 64 + lane) * SS;
    #pragma unroll
    for (int s = 0; s < SS; ++s) {
        float hb = __shfl_up(Bc[s], 1u);
        hp[s] = (lane > 0) ? hb : 0.f;
    }
}

// ---------------- S3: replay chunk with true h_start, emit y into (B,L,C)
template <int G>
__global__ __launch_bounds__(128) void k_scan_chunk2(
        const float* __restrict__ proj, const float* __restrict__ xT,
        const float* __restrict__ dtw, const float* __restrict__ dtb,
        const float* __restrict__ Alog, const float* __restrict__ Dp,
        const float* __restrict__ hstart, float* __restrict__ yT) {
    __shared__ float rs[64 * NP];
    int blk = blockIdx.x;
    int chunk = blk & 63;
    int g = (G == 4) ? ((blk >> 6) & 3) : 0;
    int b = blk / (G * 64);
    int c = threadIdx.x;
    const float* pr = proj + ((size_t)(b * G + g) * LL + chunk * 64) * NP;
    for (int i = threadIdx.x; i < 64 * NP / 4; i += 128)
        ((float4*)rs)[i] = ((const float4*)pr)[i];
    int gc = g * CC + c;
    float dwv[SS], Av[SS];
    #pragma unroll
    for (int s = 0; s < SS; ++s) {
        dwv[s] = dtw[gc * SS + s];
        Av[s] = -expf(Alog[gc * SS + s]);
    }
    float bias = dtb[gc];
    float Dv = Dp[gc];
    float h[SS];
    const float* hp = hstart + ((size_t)((b * G + g) * CC + c) * 64 + chunk) * SS;
    #pragma unroll
    for (int s = 0; s < SS; ++s) h[s] = hp[s];
    __syncthreads();
    const float* xb = xT + (size_t)b * LL * CC + c;
    float* yb = yT + (size_t)b * LL * CC + c;
    for (int k = 0; k < 64; ++k) {
        int t = chunk * 64 + k;
        int p = (G == 4) ? dmap(g, t) : t;
        float xv = xb[(size_t)p * CC];
        const float4* r4 = (const float4*)(rs + k * NP);
        float4 ra = r4[0], rb = r4[1], b0 = r4[2], b1 = r4[3], c0 = r4[4], c1 = r4[5];
        float dt = softplusf(ra.x * dwv[0] + ra.y * dwv[1] + ra.z * dwv[2] + ra.w * dwv[3] +
                             rb.x * dwv[4] + rb.y * dwv[5] + rb.z * dwv[6] + rb.w * dwv[7] + bias);
        float dx = dt * xv;
        float Bb[SS] = {b0.x, b0.y, b0.z, b0.w, b1.x, b1.y, b1.z, b1.w};
        float Cb[SS] = {c0.x, c0.y, c0.z, c0.w, c1.x, c1.y, c1.z, c1.w};
        float y = Dv * xv;
        #pragma unroll
        for (int s = 0; s < SS; ++s) {
            h[s] = fmaf(h[s], __expf(dt * Av[s]), dx * Bb[s]);
            y = fmaf(h[s], Cb[s], y);
        }
        if (G == 4) atomicAdd(yb + (size_t)p * CC, y);
        else        yb[(size_t)p * CC] = y;
    }
}

// ---------------- epilogue: [LN] -> *silu(z) -> @out_w^T ; y (B,L,C) -> dst (B,C,L)
template <bool DO_LN>
__global__ void k_epilogue(const float* __restrict__ ysrc, const float* __restrict__ zsrc,
                           const float* __restrict__ lng, const float* __restrict__ lnb,
                           const float* __restrict__ outw, float* __restrict__ dst) {
    __shared__ float yt[CC][66];
    __shared__ float mu_s[64], rs_s[64];
    int blk = blockIdx.x;
    int b = blk / (LL / 64);
    int p0 = (blk % (LL / 64)) * 64;
    int tid = threadIdx.x;
    for (int i = tid; i < CC * 64; i += 256) {
        int c = i & 127, pp = i >> 7;
        yt[c][pp] = ysrc[((size_t)b * LL + p0 + pp) * CC + c];
    }
    __syncthreads();
    if (DO_LN) {
        int pp = tid >> 2, q = tid & 3;
        float s = 0.f, ss = 0.f;
        for (int j = 0; j < 32; ++j) {
            float v = yt[q * 32 + j][pp];
            s += v; ss = fmaf(v, v, ss);
        }
        s += __shfl_xor(s, 1); ss += __shfl_xor(ss, 1);
        s += __shfl_xor(s, 2); ss += __shfl_xor(ss, 2);
        if (q == 0) {
            float mu = s * (1.f / 128.f);
            float var = ss * (1.f / 128.f) - mu * mu;
            mu_s[pp] = mu;
            rs_s[pp] = rsqrtf(var + 1e-5f);
        }
        __syncthreads();
    }
    for (int i = tid; i < CC * 64; i += 256) {
        int c = i & 127, pp = i >> 7;
        float v = yt[c][pp];
        if (DO_LN) v = fmaf((v - mu_s[pp]) * rs_s[pp], lng[c], lnb[c]);
        float zv = zsrc[((size_t)b * LL + p0 + pp) * CC + c];
        yt[c][pp] = v * siluf(zv);
    }
    __syncthreads();
    int o = tid & 127, ph = tid >> 7;
    float acc[32];
    #pragma unroll
    for (int j = 0; j < 32; ++j) acc[j] = 0.f;
    const float* wr = outw + (size_t)o * CC;
    for (int c = 0; c < CC; ++c) {
        float wv = wr[c];
        const float* row = &yt[c][ph * 32];
        #pragma unroll
        for (int j = 0; j < 32; ++j) acc[j] = fmaf(wv, row[j], acc[j]);
    }
    float* dp = dst + ((size_t)b * CC + o) * LL + p0 + ph * 32;
    #pragma unroll
    for (int j = 0; j < 32; ++j) dp[j] = acc[j];
}

// ---------------- final fusion: E0 = sigmoid(x . iw); out = (1-E0)*fi + E0*fr + x
__global__ void k_final(const float* __restrict__ x, const float* __restrict__ fi,
                        const float* __restrict__ fr, const float* __restrict__ iw,
                        float* __restrict__ out) {
    __shared__ float xt[CC][66];
    __shared__ float iws[CC];
    __shared__ float e_s[64];
    int blk = blockIdx.x;
    int b = blk / (LL / 64);
    int p0 = (blk % (LL / 64)) * 64;
    int tid = threadIdx.x;
    if (tid < CC) iws[tid] = iw[tid];
    for (int i = tid; i < CC * 64; i += 256) {
        int c = i >> 6, pp = i & 63;
        xt[c][pp] = x[((size_t)b * CC + c) * LL + p0 + pp];
    }
    __syncthreads();
    {
        int pp = tid >> 2, q = tid & 3;
        float s = 0.f;
        for (int j = 0; j < 32; ++j) {
            int c = q * 32 + j;
            s = fmaf(xt[c][pp], iws[c], s);
        }
        s += __shfl_xor(s, 1);
        s += __shfl_xor(s, 2);
        if (q == 0) e_s[pp] = 1.f / (1.f + __expf(-s));
    }
    __syncthreads();
    for (int i = tid; i < CC * 64; i += 256) {
        int c = i >> 6, pp = i & 63;
        size_t idx = ((size_t)b * CC + c) * LL + p0 + pp;
        float e = e_s[pp];
        out[idx] = (1.f - e) * fi[idx] + e * fr[idx] + xt[c][pp];
    }
}

extern "C" void kernel_launch(void* const* d_in, const int* in_sizes, int n_in,
                              void* d_out, int out_size, void* d_ws, size_t ws_size,
                              hipStream_t stream) {
    (void)in_sizes; (void)n_in; (void)out_size; (void)ws_size;
    const float* x       = (const float*)d_in[0];
    const float* s_inw   = (const float*)d_in[1];
    const float* s_convw = (const float*)d_in[2];
    const float* s_convb = (const float*)d_in[3];
    const float* s_xpw   = (const float*)d_in[4];
    const float* s_dtw   = (const float*)d_in[5];
    const float* s_dtb   = (const float*)d_in[6];
    const float* s_alog  = (const float*)d_in[7];
    const float* s_D     = (const float*)d_in[8];
    const float* s_lng   = (const float*)d_in[9];
    const float* s_lnb   = (const float*)d_in[10];
    const float* s_outw  = (const float*)d_in[11];
    const float* dw_w    = (const float*)d_in[12];
    const float* dw_b    = (const float*)d_in[13];
    const float* m_inw   = (const float*)d_in[14];
    const float* m_convw = (const float*)d_in[15];
    const float* m_convb = (const float*)d_in[16];
    const float* m_xpw   = (const float*)d_in[17];
    const float* m_dtw   = (const float*)d_in[18];
    const float* m_dtb   = (const float*)d_in[19];
    const float* m_alog  = (const float*)d_in[20];
    const float* m_D     = (const float*)d_in[21];
    const float* m_outw  = (const float*)d_in[22];
    const float* il_w    = (const float*)d_in[23];
    float* out = (float*)d_out;

    const size_t SZ1 = (size_t)BB * CC * LL;
    float* R0 = (float*)d_ws;
    float* R1 = R0 + SZ1;
    float* R2 = R1 + SZ1;
    float* R3 = R2 + SZ1;
    float* R4 = R3 + SZ1;   // up to B*4*L*24 = 3.15M floats

    dim3 blk(256);
    // ---- SS2D (global illumination) branch; f_illum lands in d_out
    k_inproj<<<BB * LL / 8, blk, 0, stream>>>(x, s_inw, R0, R1);                 // xi=R0 z=R1
    k_dwconv<<<(BB * CC * LL) / 256, blk, 0, stream>>>(R0, s_convw, s_convb, R2, 1);
    k_transpose<<<BB * 64 * 2, blk, 0, stream>>>(R2, R3);                         // xT=R3
    k_proj<4><<<BB * LL / 64, blk, 0, stream>>>(R3, s_xpw, R4);                   // pr=R4
    k_scan_chunk1<4><<<BB * 4 * 64, dim3(128), 0, stream>>>(R4, R3, s_dtw, s_dtb, s_alog, R0);
    k_scan_chain<4><<<BB * 4 * CC / 4, blk, 0, stream>>>(R0, s_alog, R2);         // hstart=R2
    hipMemsetAsync(R0, 0, SZ1 * sizeof(float), stream);                           // yT=R0
    k_scan_chunk2<4><<<BB * 4 * 64, dim3(128), 0, stream>>>(R4, R3, s_dtw, s_dtb, s_alog,
                                                            s_D, R2, R0);
    k_epilogue<true><<<BB * LL / 64, blk, 0, stream>>>(R0, R1, s_lng, s_lnb, s_outw, out);
    // ---- Mamba (local reflectance) branch
    k_dwconv<<<(BB * CC * LL) / 256, blk, 0, stream>>>(x, dw_w, dw_b, R2, 0);
    k_inproj<<<BB * LL / 8, blk, 0, stream>>>(R2, m_inw, R0, R1);                 // xi=R0 z=R1
    k_conv1d<<<(BB * CC * LL) / 256, blk, 0, stream>>>(R0, m_convw, m_convb, R2);
    k_transpose<<<BB * 64 * 2, blk, 0, stream>>>(R2, R3);                         // xT=R3
    k_proj<1><<<BB * LL / 64, blk, 0, stream>>>(R3, m_xpw, R4);
    k_scan_chunk1<1><<<BB * 64, dim3(128), 0, stream>>>(R4, R3, m_dtw, m_dtb, m_alog, R0);
    k_scan_chain<1><<<BB * CC / 4, blk, 0, stream>>>(R0, m_alog, R2);             // hstart=R2
    k_scan_chunk2<1><<<BB * 64, dim3(128), 0, stream>>>(R4, R3, m_dtw, m_dtb, m_alog,
                                                        m_D, R2, R0);             // yT=R0
    k_epilogue<false><<<BB * LL / 64, blk, 0, stream>>>(R0, R1, s_lng, s_lnb, m_outw, R2);
    // ---- physics-prior gated fusion (+x)
    k_final<<<BB * LL / 64, blk, 0, stream>>>(x, out, R2, il_w, out);
}

// Round 3
// 482.330 us; speedup vs baseline: 2.5526x; 1.2744x over previous
//
#include <hip/hip_runtime.h>
#include <math.h>

#define BB 8
#define CC 128
#define LL 4096
#define NP 24   // dt_rank(8) + 2*d_state(8)
#define SS 8

__device__ __forceinline__ float siluf(float x) { return x / (1.f + __expf(-x)); }
__device__ __forceinline__ float softplusf(float x) {
    return (x > 15.f) ? x : __logf(1.f + __expf(x));
}

// scan-index t -> spatial position p for direction g
__device__ __forceinline__ int dmap(int g, int t) {
    switch (g) {
        case 0: return t;
        case 1: return ((t & 63) << 6) | (t >> 6);
        case 2: return (LL - 1) - t;
        default: { int u = (LL - 1) - t; return ((u & 63) << 6) | (u >> 6); }
    }
}
// spatial position p -> scan index l for direction g
__device__ __forceinline__ int smap(int g, int p) {
    switch (g) {
        case 0: return p;
        case 1: return ((p & 63) << 6) | (p >> 6);
        case 2: return (LL - 1) - p;
        default: return (LL - 1) - (((p & 63) << 6) | (p >> 6)); }
}

// ---------------- in_proj: (B,C,L) @ W(256,128)^T -> xi (B,C,L), z (B,L,C)
// register-tiled GEMM: block = 32 pos x 256 out, K sliced by 32
__global__ __launch_bounds__(256) void k_inproj(const float* __restrict__ src,
                                                const float* __restrict__ w,
                                                float* __restrict__ xi,
                                                float* __restrict__ z) {
    __shared__ float xs[32][32];    // [kk][pos]
    __shared__ float ws[32][260];   // [kk][out] padded
    int blk = blockIdx.x;
    int b = blk / (LL / 32);
    int p0 = (blk % (LL / 32)) * 32;
    int tid = threadIdx.x;
    int pg = tid & 7;    // pos group: 4 pos
    int og = tid >> 3;   // out group: 8 out
    float acc[8][4];
    #pragma unroll
    for (int j = 0; j < 8; ++j)
        #pragma unroll
        for (int i = 0; i < 4; ++i) acc[j][i] = 0.f;
    for (int k0 = 0; k0 < CC; k0 += 32) {
        for (int i = tid; i < 32 * 32; i += 256) {
            int kk = i >> 5, p = i & 31;
            xs[kk][p] = src[((size_t)b * CC + k0 + kk) * LL + p0 + p];
        }
        for (int i = tid; i < 32 * 256; i += 256) {
            int o = i >> 5, kk = i & 31;
            ws[kk][o] = w[(size_t)o * CC + k0 + kk];
        }
        __syncthreads();
        #pragma unroll 4
        for (int kk = 0; kk < 32; ++kk) {
            float4 xv = *(const float4*)&xs[kk][pg * 4];
            float4 wa = *(const float4*)&ws[kk][og * 8];
            float4 wb = *(const float4*)&ws[kk][og * 8 + 4];
            float wj[8] = {wa.x, wa.y, wa.z, wa.w, wb.x, wb.y, wb.z, wb.w};
            float xv4[4] = {xv.x, xv.y, xv.z, xv.w};
            #pragma unroll
            for (int j = 0; j < 8; ++j)
                #pragma unroll
                for (int i = 0; i < 4; ++i) acc[j][i] = fmaf(wj[j], xv4[i], acc[j][i]);
        }
        __syncthreads();
    }
    if (og < 16) {
        float* xp = xi + ((size_t)b * CC + og * 8) * LL + p0 + pg * 4;
        #pragma unroll
        for (int j = 0; j < 8; ++j) {
            float4 v = {acc[j][0], acc[j][1], acc[j][2], acc[j][3]};
            *(float4*)(xp + (size_t)j * LL) = v;
        }
    } else {
        int oz = (og - 16) * 8;
        float* zp = z + ((size_t)b * LL + p0 + pg * 4) * CC + oz;
        #pragma unroll
        for (int i = 0; i < 4; ++i) {
            float4 v0 = {acc[0][i], acc[1][i], acc[2][i], acc[3][i]};
            float4 v1 = {acc[4][i], acc[5][i], acc[6][i], acc[7][i]};
            *(float4*)(zp + (size_t)i * CC) = v0;
            *(float4*)(zp + (size_t)i * CC + 4) = v1;
        }
    }
}

// ---------------- depthwise 3x3 conv, pad 1, (B,C,64,64); optional silu
__global__ void k_dwconv(const float* __restrict__ src, const float* __restrict__ w,
                         const float* __restrict__ bias, float* __restrict__ dst,
                         int do_silu) {
    int idx = blockIdx.x * 256 + threadIdx.x;
    int p = idx & (LL - 1);
    int c = (idx >> 12) & (CC - 1);
    int b = idx >> 19;
    int h = p >> 6, w0 = p & 63;
    const float* sp = src + ((size_t)b * CC + c) * LL;
    const float* wc = w + c * 9;
    float acc = bias[c];
    #pragma unroll
    for (int kh = 0; kh < 3; ++kh) {
        int hh = h + kh - 1;
        if ((unsigned)hh < 64u) {
            #pragma unroll
            for (int kw = 0; kw < 3; ++kw) {
                int ww = w0 + kw - 1;
                if ((unsigned)ww < 64u) acc = fmaf(sp[hh * 64 + ww], wc[kh * 3 + kw], acc);
            }
        }
    }
    if (do_silu) acc = siluf(acc);
    dst[idx] = acc;
}

// ---------------- causal depthwise conv1d k=4 + bias + silu, (B,C,L)
__global__ void k_conv1d(const float* __restrict__ src, const float* __restrict__ w,
                         const float* __restrict__ bias, float* __restrict__ dst) {
    int idx = blockIdx.x * 256 + threadIdx.x;
    int l = idx & (LL - 1);
    int c = (idx >> 12) & (CC - 1);
    int b = idx >> 19;
    const float* sp = src + ((size_t)b * CC + c) * LL;
    const float* wc = w + c * 4;
    float acc = bias[c];
    #pragma unroll
    for (int k = 0; k < 4; ++k) {
        int ll = l - 3 + k;
        if (ll >= 0) acc = fmaf(sp[ll], wc[k], acc);
    }
    dst[idx] = siluf(acc);
}

// ---------------- tiled transpose (B,C,L) -> (B,L,C)
__global__ void k_transpose(const float* __restrict__ src, float* __restrict__ dst) {
    __shared__ float t[64][65];
    int blk = blockIdx.x;
    int ct = blk & 1;
    int pt = (blk >> 1) & 63;
    int b  = blk >> 7;
    int c0 = ct * 64, p0 = pt * 64;
    int tid = threadIdx.x;
    int px = tid & 63, r0 = tid >> 6;
    for (int r = r0; r < 64; r += 4)
        t[r][px] = src[((size_t)b * CC + c0 + r) * LL + p0 + px];
    __syncthreads();
    for (int r = r0; r < 64; r += 4)
        dst[((size_t)b * LL + p0 + r) * CC + c0 + px] = t[px][r];
}

// ---------------- x_proj: xT (B,L,C) -> proj (B,G,L,24) in scan order
template <int G>
__global__ void k_proj(const float* __restrict__ src, const float* __restrict__ w,
                       float* __restrict__ dst) {
    __shared__ float xt[CC][66];
    __shared__ float prj[G][64][NP];
    int blk = blockIdx.x;
    int b = blk / (LL / 64);
    int p0 = (blk % (LL / 64)) * 64;
    int tid = threadIdx.x;
    for (int i = tid; i < CC * 64; i += 256) {
        int c = i & 127, pp = i >> 7;
        xt[c][pp] = src[((size_t)b * LL + p0 + pp) * CC + c];
    }
    __syncthreads();
    const int PAIRS = G * NP;
    const int PER = PAIRS / 4;
    int pp = tid & 63;
    int bp = tid >> 6;
    float acc[PER];
    #pragma unroll
    for (int j = 0; j < PER; ++j) acc[j] = 0.f;
    for (int c = 0; c < CC; ++c) {
        float xv = xt[c][pp];
        #pragma unroll
        for (int j = 0; j < PER; ++j)
            acc[j] = fmaf(w[(bp + j * 4) * CC + c], xv, acc[j]);
    }
    #pragma unroll
    for (int j = 0; j < PER; ++j) {
        int pair = bp + j * 4;
        prj[pair / NP][pp][pair % NP] = acc[j];
    }
    __syncthreads();
    for (int i = tid; i < G * 64 * NP; i += 256) {
        int d = i % NP;
        int rest = i / NP;
        int ppp = rest & 63;
        int g = rest >> 6;
        int p = p0 + ppp;
        int l = (G == 4) ? smap(g, p) : p;
        dst[((size_t)(b * G + g) * LL + l) * NP + d] = prj[g][ppp][d];
    }
}

// ---------------- S1: per-chunk local scan (h0=0) -> summaries (sumdt, h[8])
template <int G>
__global__ __launch_bounds__(128) void k_scan_chunk1(
        const float* __restrict__ proj, const float* __restrict__ xT,
        const float* __restrict__ dtw, const float* __restrict__ dtb,
        const float* __restrict__ Alog, float* __restrict__ summ) {
    __shared__ float rs[64 * NP];
    int blk = blockIdx.x;
    int chunk = blk & 63;
    int g = (G == 4) ? ((blk >> 6) & 3) : 0;
    int b = blk / (G * 64);
    int c = threadIdx.x;
    const float* pr = proj + ((size_t)(b * G + g) * LL + chunk * 64) * NP;
    for (int i = threadIdx.x; i < 64 * NP / 4; i += 128)
        ((float4*)rs)[i] = ((const float4*)pr)[i];
    int gc = g * CC + c;
    float dwv[SS], Av[SS];
    #pragma unroll
    for (int s = 0; s < SS; ++s) {
        dwv[s] = dtw[gc * SS + s];
        Av[s] = -expf(Alog[gc * SS + s]);
    }
    float bias = dtb[gc];
    __syncthreads();
    float h[SS];
    #pragma unroll
    for (int s = 0; s < SS; ++s) h[s] = 0.f;
    float sumdt = 0.f;
    const float* xb = xT + (size_t)b * LL * CC + c;
    for (int k = 0; k < 64; ++k) {
        int t = chunk * 64 + k;
        int p = (G == 4) ? dmap(g, t) : t;
        float xv = xb[(size_t)p * CC];
        const float4* r4 = (const float4*)(rs + k * NP);
        float4 ra = r4[0], rb = r4[1], b0 = r4[2], b1 = r4[3];
        float dt = softplusf(ra.x * dwv[0] + ra.y * dwv[1] + ra.z * dwv[2] + ra.w * dwv[3] +
                             rb.x * dwv[4] + rb.y * dwv[5] + rb.z * dwv[6] + rb.w * dwv[7] + bias);
        sumdt += dt;
        float dx = dt * xv;
        float Bb[SS] = {b0.x, b0.y, b0.z, b0.w, b1.x, b1.y, b1.z, b1.w};
        #pragma unroll
        for (int s = 0; s < SS; ++s) h[s] = fmaf(h[s], __expf(dt * Av[s]), dx * Bb[s]);
    }
    float* sp = summ + ((size_t)((b * G + g) * CC + c) * 64 + chunk) * 9;
    sp[0] = sumdt;
    #pragma unroll
    for (int s = 0; s < SS; ++s) sp[1 + s] = h[s];
}

// ---------------- S2: cross-chunk shuffle scan -> h_start per chunk
template <int G>
__global__ __launch_bounds__(256) void k_scan_chain(
        const float* __restrict__ summ, const float* __restrict__ Alog,
        float* __restrict__ hstart) {
    int wid = threadIdx.x >> 6, lane = threadIdx.x & 63;
    int chain = blockIdx.x * 4 + wid;
    int c = chain & 127;
    int g = (G == 4) ? ((chain >> 7) & 3) : 0;
    int gc = g * CC + c;
    float Av[SS];
    #pragma unroll
    for (int s = 0; s < SS; ++s) Av[s] = -expf(Alog[gc * SS + s]);
    const float* sp = summ + ((size_t)chain * 64 + lane) * 9;
    float sumdt = sp[0];
    float Ac[SS], Bc[SS];
    #pragma unroll
    for (int s = 0; s < SS; ++s) { Ac[s] = __expf(Av[s] * sumdt); Bc[s] = sp[1 + s]; }
    #pragma unroll
    for (int off = 1; off < 64; off <<= 1) {
        #pragma unroll
        for (int s = 0; s < SS; ++s) {
            float Ap = __shfl_up(Ac[s], (unsigned)off);
            float Bp = __shfl_up(Bc[s], (unsigned)off);
            if (lane >= off) { Bc[s] = fmaf(Bp, Ac[s], Bc[s]); Ac[s] *= Ap; }
        }
    }
    float* hp = hstart + ((size_t)chain * 64 + lane) * SS;
    #pragma unroll
    for (int s = 0; s < SS; ++s) {
        float hb = __shfl_up(Bc[s], 1u);
        hp[s] = (lane > 0) ? hb : 0.f;
    }
}

// ---------------- S3: replay chunk with true h_start, emit y into (B,L,C)
template <int G>
__global__ __launch_bounds__(128) void k_scan_chunk2(
        const float* __restrict__ proj, const float* __restrict__ xT,
        const float* __restrict__ dtw, const float* __restrict__ dtb,
        const float* __restrict__ Alog, const float* __restrict__ Dp,
        const float* __restrict__ hstart, float* __restrict__ yT) {
    __shared__ float rs[64 * NP];
    int blk = blockIdx.x;
    int chunk = blk & 63;
    int g = (G == 4) ? ((blk >> 6) & 3) : 0;
    int b = blk / (G * 64);
    int c = threadIdx.x;
    const float* pr = proj + ((size_t)(b * G + g) * LL + chunk * 64) * NP;
    for (int i = threadIdx.x; i < 64 * NP / 4; i += 128)
        ((float4*)rs)[i] = ((const float4*)pr)[i];
    int gc = g * CC + c;
    float dwv[SS], Av[SS];
    #pragma unroll
    for (int s = 0; s < SS; ++s) {
        dwv[s] = dtw[gc * SS + s];
        Av[s] = -expf(Alog[gc * SS + s]);
    }
    float bias = dtb[gc];
    float Dv = Dp[gc];
    float h[SS];
    const float* hp = hstart + ((size_t)((b * G + g) * CC + c) * 64 + chunk) * SS;
    #pragma unroll
    for (int s = 0; s < SS; ++s) h[s] = hp[s];
    __syncthreads();
    const float* xb = xT + (size_t)b * LL * CC + c;
    float* yb = yT + (size_t)b * LL * CC + c;
    for (int k = 0; k < 64; ++k) {
        int t = chunk * 64 + k;
        int p = (G == 4) ? dmap(g, t) : t;
        float xv = xb[(size_t)p * CC];
        const float4* r4 = (const float4*)(rs + k * NP);
        float4 ra = r4[0], rb = r4[1], b0 = r4[2], b1 = r4[3], c0 = r4[4], c1 = r4[5];
        float dt = softplusf(ra.x * dwv[0] + ra.y * dwv[1] + ra.z * dwv[2] + ra.w * dwv[3] +
                             rb.x * dwv[4] + rb.y * dwv[5] + rb.z * dwv[6] + rb.w * dwv[7] + bias);
        float dx = dt * xv;
        float Bb[SS] = {b0.x, b0.y, b0.z, b0.w, b1.x, b1.y, b1.z, b1.w};
        float Cb[SS] = {c0.x, c0.y, c0.z, c0.w, c1.x, c1.y, c1.z, c1.w};
        float y = Dv * xv;
        #pragma unroll
        for (int s = 0; s < SS; ++s) {
            h[s] = fmaf(h[s], __expf(dt * Av[s]), dx * Bb[s]);
            y = fmaf(h[s], Cb[s], y);
        }
        if (G == 4) atomicAdd(yb + (size_t)p * CC, y);
        else        yb[(size_t)p * CC] = y;
    }
}

// ---------------- epilogue: [LN] -> *silu(z) -> @out_w^T ; y (B,L,C) -> dst (B,C,L)
template <bool DO_LN>
__global__ __launch_bounds__(256) void k_epilogue(
        const float* __restrict__ ysrc, const float* __restrict__ zsrc,
        const float* __restrict__ lng, const float* __restrict__ lnb,
        const float* __restrict__ outw, float* __restrict__ dst) {
    __shared__ float yt[CC][68];
    __shared__ float ws[32][132];
    __shared__ float mu_s[64], rs_s[64];
    int blk = blockIdx.x;
    int b = blk / (LL / 64);
    int p0 = (blk % (LL / 64)) * 64;
    int tid = threadIdx.x;
    for (int i = tid; i < CC * 64; i += 256) {
        int c = i & 127, pp = i >> 7;
        yt[c][pp] = ysrc[((size_t)b * LL + p0 + pp) * CC + c];
    }
    __syncthreads();
    if (DO_LN) {
        int pp = tid >> 2, q = tid & 3;
        float s = 0.f, ss = 0.f;
        for (int j = 0; j < 32; ++j) {
            float v = yt[q * 32 + j][pp];
            s += v; ss = fmaf(v, v, ss);
        }
        s += __shfl_xor(s, 1); ss += __shfl_xor(ss, 1);
        s += __shfl_xor(s, 2); ss += __shfl_xor(ss, 2);
        if (q == 0) {
            float mu = s * (1.f / 128.f);
            float var = ss * (1.f / 128.f) - mu * mu;
            mu_s[pp] = mu;
            rs_s[pp] = rsqrtf(var + 1e-5f);
        }
        __syncthreads();
    }
    for (int i = tid; i < CC * 64; i += 256) {
        int c = i & 127, pp = i >> 7;
        float v = yt[c][pp];
        if (DO_LN) v = fmaf((v - mu_s[pp]) * rs_s[pp], lng[c], lnb[c]);
        float zv = zsrc[((size_t)b * LL + p0 + pp) * CC + c];
        yt[c][pp] = v * siluf(zv);
    }
    // GEMM: 64 pos x 128 out, K=128 sliced by 32
    int pg = tid & 15;   // 4 pos
    int og = tid >> 4;   // 8 out
    float acc[8][4];
    #pragma unroll
    for (int j = 0; j < 8; ++j)
        #pragma unroll
        for (int i = 0; i < 4; ++i) acc[j][i] = 0.f;
    for (int k0 = 0; k0 < CC; k0 += 32) {
        __syncthreads();
        for (int i = tid; i < 32 * 128; i += 256) {
            int o = i >> 5, kk = i & 31;
            ws[kk][o] = outw[(size_t)o * CC + k0 + kk];
        }
        __syncthreads();
        #pragma unroll 4
        for (int kk = 0; kk < 32; ++kk) {
            float4 xv = *(const float4*)&yt[k0 + kk][pg * 4];
            float4 wa = *(const float4*)&ws[kk][og * 8];
            float4 wb = *(const float4*)&ws[kk][og * 8 + 4];
            float wj[8] = {wa.x, wa.y, wa.z, wa.w, wb.x, wb.y, wb.z, wb.w};
            float xv4[4] = {xv.x, xv.y, xv.z, xv.w};
            #pragma unroll
            for (int j = 0; j < 8; ++j)
                #pragma unroll
                for (int i = 0; i < 4; ++i) acc[j][i] = fmaf(wj[j], xv4[i], acc[j][i]);
        }
    }
    float* dp = dst + ((size_t)b * CC + og * 8) * LL + p0 + pg * 4;
    #pragma unroll
    for (int j = 0; j < 8; ++j) {
        float4 v = {acc[j][0], acc[j][1], acc[j][2], acc[j][3]};
        *(float4*)(dp + (size_t)j * LL) = v;
    }
}

// ---------------- final fusion: E0 = sigmoid(x . iw); out = (1-E0)*fi + E0*fr + x
__global__ void k_final(const float* __restrict__ x, const float* __restrict__ fi,
                        const float* __restrict__ fr, const float* __restrict__ iw,
                        float* __restrict__ out) {
    __shared__ float xt[CC][66];
    __shared__ float iws[CC];
    __shared__ float e_s[64];
    int blk = blockIdx.x;
    int b = blk / (LL / 64);
    int p0 = (blk % (LL / 64)) * 64;
    int tid = threadIdx.x;
    if (tid < CC) iws[tid] = iw[tid];
    for (int i = tid; i < CC * 64; i += 256) {
        int c = i >> 6, pp = i & 63;
        xt[c][pp] = x[((size_t)b * CC + c) * LL + p0 + pp];
    }
    __syncthreads();
    {
        int pp = tid >> 2, q = tid & 3;
        float s = 0.f;
        for (int j = 0; j < 32; ++j) {
            int c = q * 32 + j;
            s = fmaf(xt[c][pp], iws[c], s);
        }
        s += __shfl_xor(s, 1);
        s += __shfl_xor(s, 2);
        if (q == 0) e_s[pp] = 1.f / (1.f + __expf(-s));
    }
    __syncthreads();
    for (int i = tid; i < CC * 64; i += 256) {
        int c = i >> 6, pp = i & 63;
        size_t idx = ((size_t)b * CC + c) * LL + p0 + pp;
        float e = e_s[pp];
        out[idx] = (1.f - e) * fi[idx] + e * fr[idx] + xt[c][pp];
    }
}

extern "C" void kernel_launch(void* const* d_in, const int* in_sizes, int n_in,
                              void* d_out, int out_size, void* d_ws, size_t ws_size,
                              hipStream_t stream) {
    (void)in_sizes; (void)n_in; (void)out_size; (void)ws_size;
    const float* x       = (const float*)d_in[0];
    const float* s_inw   = (const float*)d_in[1];
    const float* s_convw = (const float*)d_in[2];
    const float* s_convb = (const float*)d_in[3];
    const float* s_xpw   = (const float*)d_in[4];
    const float* s_dtw   = (const float*)d_in[5];
    const float* s_dtb   = (const float*)d_in[6];
    const float* s_alog  = (const float*)d_in[7];
    const float* s_D     = (const float*)d_in[8];
    const float* s_lng   = (const float*)d_in[9];
    const float* s_lnb   = (const float*)d_in[10];
    const float* s_outw  = (const float*)d_in[11];
    const float* dw_w    = (const float*)d_in[12];
    const float* dw_b    = (const float*)d_in[13];
    const float* m_inw   = (const float*)d_in[14];
    const float* m_convw = (const float*)d_in[15];
    const float* m_convb = (const float*)d_in[16];
    const float* m_xpw   = (const float*)d_in[17];
    const float* m_dtw   = (const float*)d_in[18];
    const float* m_dtb   = (const float*)d_in[19];
    const float* m_alog  = (const float*)d_in[20];
    const float* m_D     = (const float*)d_in[21];
    const float* m_outw  = (const float*)d_in[22];
    const float* il_w    = (const float*)d_in[23];
    float* out = (float*)d_out;

    const size_t SZ1 = (size_t)BB * CC * LL;
    float* R0 = (float*)d_ws;
    float* R1 = R0 + SZ1;
    float* R2 = R1 + SZ1;
    float* R3 = R2 + SZ1;
    float* R4 = R3 + SZ1;

    dim3 blk(256);
    // ---- SS2D (global illumination) branch; f_illum lands in d_out
    k_inproj<<<BB * LL / 32, blk, 0, stream>>>(x, s_inw, R0, R1);                 // xi=R0 z=R1
    k_dwconv<<<(BB * CC * LL) / 256, blk, 0, stream>>>(R0, s_convw, s_convb, R2, 1);
    k_transpose<<<BB * 64 * 2, blk, 0, stream>>>(R2, R3);                         // xT=R3
    k_proj<4><<<BB * LL / 64, blk, 0, stream>>>(R3, s_xpw, R4);                   // pr=R4
    k_scan_chunk1<4><<<BB * 4 * 64, dim3(128), 0, stream>>>(R4, R3, s_dtw, s_dtb, s_alog, R0);
    k_scan_chain<4><<<BB * 4 * CC / 4, blk, 0, stream>>>(R0, s_alog, R2);         // hstart=R2
    hipMemsetAsync(R0, 0, SZ1 * sizeof(float), stream);                           // yT=R0
    k_scan_chunk2<4><<<BB * 4 * 64, dim3(128), 0, stream>>>(R4, R3, s_dtw, s_dtb, s_alog,
                                                            s_D, R2, R0);
    k_epilogue<true><<<BB * LL / 64, blk, 0, stream>>>(R0, R1, s_lng, s_lnb, s_outw, out);
    // ---- Mamba (local reflectance) branch
    k_dwconv<<<(BB * CC * LL) / 256, blk, 0, stream>>>(x, dw_w, dw_b, R2, 0);
    k_inproj<<<BB * LL / 32, blk, 0, stream>>>(R2, m_inw, R0, R1);                // xi=R0 z=R1
    k_conv1d<<<(BB * CC * LL) / 256, blk, 0, stream>>>(R0, m_convw, m_convb, R2);
    k_transpose<<<BB * 64 * 2, blk, 0, stream>>>(R2, R3);                         // xT=R3
    k_proj<1><<<BB * LL / 64, blk, 0, stream>>>(R3, m_xpw, R4);
    k_scan_chunk1<1><<<BB * 64, dim3(128), 0, stream>>>(R4, R3, m_dtw, m_dtb, m_alog, R0);
    k_scan_chain<1><<<BB * CC / 4, blk, 0, stream>>>(R0, m_alog, R2);             // hstart=R2
    k_scan_chunk2<1><<<BB * 64, dim3(128), 0, stream>>>(R4, R3, m_dtw, m_dtb, m_alog,
                                                        m_D, R2, R0);             // yT=R0
    k_epilogue<false><<<BB * LL / 64, blk, 0, stream>>>(R0, R1, s_lng, s_lnb, m_outw, R2);
    // ---- physics-prior gated fusion (+x)
    k_final<<<BB * LL / 64, blk, 0, stream>>>(x, out, R2, il_w, out);
}